// Round 10
// baseline (52.985 us; speedup 1.0000x reference)
//
#include <hip/hip_runtime.h>

#define NN 128
#define CCH 16
#define BB 4
#define HID 128
#define DOUT 128

typedef float v2f __attribute__((ext_vector_type(2)));

// ws float offsets
#define XT_OFF   0u            // 1,048,576 floats (4 MiB) transpose
#define XD_OFF   1048576u      // 8,192 floats diagonals
#define WPK_OFF  1064960u      // 1,024 floats ([128][8] packed weights)
#define H1_OFF   2097152u      // 1,048,576 floats h1 values
#define DG_OFF   4194304u      // 16,384 floats diag partials [b][c][p][qh]

// ---------------------------------------------------------------------------
// prep: pack weights into [k][8] = {w0,w1,w2,w3,b1,w20,w21,0}   (R7 verbatim)
// ---------------------------------------------------------------------------
__global__ void prep_weights(const float* __restrict__ W1, const float* __restrict__ b1,
                             const float* __restrict__ W2, float* __restrict__ wpk)
{
    const int k = threadIdx.x;
    const float4 w = reinterpret_cast<const float4*>(W1)[k];
    wpk[k * 8 + 0] = w.x;  wpk[k * 8 + 1] = w.y;
    wpk[k * 8 + 2] = w.z;  wpk[k * 8 + 3] = w.w;
    wpk[k * 8 + 4] = b1[k];
    wpk[k * 8 + 5] = W2[k];
    wpk[k * 8 + 6] = W2[HID + k];
    wpk[k * 8 + 7] = 0.f;
}

// ---------------------------------------------------------------------------
// xpose: per (b,c,32-row stripe) transpose -> xT, diagonal -> xd (R7 verbatim)
// ---------------------------------------------------------------------------
__global__ __launch_bounds__(512) void xpose_diag(
    const float* __restrict__ x, float* __restrict__ xT, float* __restrict__ xd)
{
    __shared__ float tile[32][NN + 1];
    const int t  = threadIdx.x;
    const int bid = blockIdx.x;
    const int st = bid & 3;
    const int c  = (bid >> 2) & 15;
    const int b  = bid >> 6;
    const int q0 = st * 32;
    const float* xm = x + ((size_t)(b * CCH + c) << 14);

    #pragma unroll
    for (int pass = 0; pass < 2; ++pass) {
        const int i = (t >> 5) + pass * 16;
        const int m = (t & 31) * 4;
        const float4 v = *reinterpret_cast<const float4*>(&xm[(q0 + i) * NN + m]);
        tile[i][m] = v.x; tile[i][m+1] = v.y; tile[i][m+2] = v.z; tile[i][m+3] = v.w;
    }
    __syncthreads();
    if (t < 32) xd[(b * CCH + c) * NN + q0 + t] = tile[t][q0 + t];
    float* xTm = xT + ((size_t)(b * CCH + c) << 14);
    const int p = t >> 2;
    #pragma unroll
    for (int g = 0; g < 2; ++g) {
        const int qq = (t & 3) * 8 + g * 4;
        float4 v;
        v.x = tile[qq+0][p]; v.y = tile[qq+1][p]; v.z = tile[qq+2][p]; v.w = tile[qq+3][p];
        *reinterpret_cast<float4*>(&xTm[p * NN + q0 + qq]) = v;
    }
}

// ---------------------------------------------------------------------------
// k1: phase 1. Block = (b, p, q-half). 256 threads, 4 waves, NO LDS/barriers.
// Wave = channel-group cg = t>>6 (wave-uniform); lane covers q = qh*64+(t&63).
// Each thread: 4 channels (2 v2f), 1 q. h1 -> ws, per-wave diag partial -> ws.
// (R7 verbatim — the empirically-fast codegen shape: s_load weights,
// wave-uniform xpp, coalesced per-channel x rows.)
// ---------------------------------------------------------------------------
__global__ void k1_phase1(
    const float* __restrict__ x, const float* __restrict__ xT,
    const float* __restrict__ xd, const float* __restrict__ wpk,
    const float* __restrict__ b2,
    float* __restrict__ h1ws, float* __restrict__ dgws)
{
    const int t   = threadIdx.x;
    const int bid = blockIdx.x;
    const int qh  = bid & 1;
    const int p   = (bid >> 1) & 127;
    const int b   = bid >> 8;
    const int q   = qh * 64 + (t & 63);
    const int cg  = t >> 6;               // 0..3 (wave-uniform)

    const float bb0 = b2[0], bb1 = b2[1];
    const v2f z2 = { 0.f, 0.f };

    v2f xpq2[2], xqp2[2], xqq2[2], xpp2[2];
    #pragma unroll
    for (int g = 0; g < 2; ++g)
        #pragma unroll
        for (int e = 0; e < 2; ++e) {
            const int c = cg * 4 + 2 * g + e;
            const size_t mbase = (size_t)(b * CCH + c) << 14;
            xpq2[g][e] = x [mbase + p * NN + q];
            xqp2[g][e] = xT[mbase + p * NN + q];
            xqq2[g][e] = xd[(b * CCH + c) * NN + q];
            xpp2[g][e] = xd[(b * CCH + c) * NN + p];   // wave-uniform
        }

    v2f h0_2[2] = { { bb0, bb0 }, { bb0, bb0 } };
    v2f h1_2[2] = { { bb1, bb1 }, { bb1, bb1 } };

    const float4* wp4 = reinterpret_cast<const float4*>(wpk);
    #pragma unroll 4
    for (int k = 0; k < HID; ++k) {
        const float4 wA = wp4[2 * k];       // w0 w1 w2 w3   (uniform -> s_load)
        const float4 wB = wp4[2 * k + 1];   // b1 w20 w21 -
        const v2f wx = { wA.x, wA.x }, wy = { wA.y, wA.y };
        const v2f wz = { wA.z, wA.z }, ww = { wA.w, wA.w };
        const v2f bk = { wB.x, wB.x };
        const v2f w20 = { wB.y, wB.y }, w21 = { wB.z, wB.z };
        #pragma unroll
        for (int g = 0; g < 2; ++g) {
            v2f hd = __builtin_elementwise_fma(wx, xpp2[g], bk);
            hd = __builtin_elementwise_fma(wy, xpq2[g], hd);
            hd = __builtin_elementwise_fma(wz, xqp2[g], hd);
            hd = __builtin_elementwise_fma(ww, xqq2[g], hd);
            hd = __builtin_elementwise_max(hd, z2);
            h0_2[g] = __builtin_elementwise_fma(w20, hd, h0_2[g]);
            h1_2[g] = __builtin_elementwise_fma(w21, hd, h1_2[g]);
        }
    }

    float h0s[4];
    #pragma unroll
    for (int g = 0; g < 2; ++g)
        #pragma unroll
        for (int e = 0; e < 2; ++e) {
            const int c = cg * 4 + 2 * g + e;
            h1ws[((size_t)(b * CCH + c) * NN + p) * NN + q] = h1_2[g][e];
            h0s[2 * g + e] = (q == p) ? 0.f : h0_2[g][e];
        }

    #pragma unroll
    for (int e = 0; e < 4; ++e) {
        float v = h0s[e];
        for (int off = 32; off > 0; off >>= 1)
            v += __shfl_down(v, off, 64);
        if ((t & 63) == 0) {
            const int c = cg * 4 + e;
            dgws[((b * CCH + c) * NN + p) * 2 + qh] = v;
        }
    }
}

// ---------------------------------------------------------------------------
// k2: phase 2. Block = (b, p). 256 threads, 4 waves. Stage h1-row + diag fix
// in LDS, then channel mix 16->128 + ReLU, streamed to y. (R7 verbatim)
// ---------------------------------------------------------------------------
__global__ void k2_phase2(
    const float* __restrict__ h1ws, const float* __restrict__ dgws,
    const float* __restrict__ Wc, const float* __restrict__ bc,
    float* __restrict__ y)
{
    __shared__ float s_out[CCH][NN];   // 8 KB
    const int t   = threadIdx.x;
    const int bid = blockIdx.x;
    const int p   = bid & 127;
    const int b   = bid >> 7;

    #pragma unroll
    for (int i = 0; i < 8; ++i) {
        const int idx = t + i * 256;
        const int c = idx >> 7, m = idx & 127;
        s_out[c][m] = h1ws[((size_t)(b * CCH + c) * NN + p) * NN + m];
    }
    __syncthreads();
    if (t < CCH) {
        const int c = t;
        const float d0 = dgws[((b * CCH + c) * NN + p) * 2 + 0];
        const float d1 = dgws[((b * CCH + c) * NN + p) * 2 + 1];
        s_out[c][p] = (d0 + d1) * (1.0f / (NN - 1));
    }
    __syncthreads();

    const int lane = t & 63;
    const int wv   = t >> 6;           // 0..3 -> 32 d's each
    const int m0   = lane * 2;
    const v2f z2 = { 0.f, 0.f };
    v2f r[CCH];
    #pragma unroll
    for (int c = 0; c < CCH; ++c)
        r[c] = *reinterpret_cast<const v2f*>(&s_out[c][m0]);

    #pragma unroll 4
    for (int dd = 0; dd < 32; ++dd) {
        const int d = wv * 32 + dd;            // wave-uniform
        const float bcv = bc[d];
        v2f acc = { bcv, bcv };
        #pragma unroll
        for (int c = 0; c < CCH; ++c) {
            const float wcf = Wc[d * CCH + c]; // uniform -> scalar
            const v2f wcv = { wcf, wcf };
            acc = __builtin_elementwise_fma(wcv, r[c], acc);
        }
        acc = __builtin_elementwise_max(acc, z2);
        float* yp = y + ((((size_t)(b * DOUT + d)) * NN + p) * NN + m0);
        *reinterpret_cast<v2f*>(yp) = acc;
    }
}

extern "C" void kernel_launch(void* const* d_in, const int* in_sizes, int n_in,
                              void* d_out, int out_size, void* d_ws, size_t ws_size,
                              hipStream_t stream) {
    const float* x  = (const float*)d_in[0];
    const float* W1 = (const float*)d_in[1];
    const float* b1 = (const float*)d_in[2];
    const float* W2 = (const float*)d_in[3];
    const float* b2 = (const float*)d_in[4];
    const float* Wc = (const float*)d_in[5];
    const float* bc = (const float*)d_in[6];
    float* y  = (float*)d_out;
    float* ws = (float*)d_ws;

    float* xT  = ws + XT_OFF;
    float* xd  = ws + XD_OFF;
    float* wpk = ws + WPK_OFF;
    float* h1w = ws + H1_OFF;
    float* dgw = ws + DG_OFF;

    prep_weights<<<dim3(1), 128, 0, stream>>>(W1, b1, W2, wpk);
    xpose_diag<<<dim3(BB * CCH * 4), 512, 0, stream>>>(x, xT, xd);
    k1_phase1<<<dim3(BB * NN * 2), 256, 0, stream>>>(x, xT, xd, wpk, b2, h1w, dgw);
    k2_phase2<<<dim3(BB * NN), 256, 0, stream>>>(h1w, dgw, Wc, bc, y);
}

// Round 11
// 37.473 us; speedup vs baseline: 1.4139x; 1.4139x over previous
//
#include <hip/hip_runtime.h>

#define NN 128
#define CCH 16
#define BB 4
#define HID 128
#define DOUT 128

typedef float v2f __attribute__((ext_vector_type(2)));

// ---------------------------------------------------------------------------
// Single fused kernel. Block = (b, row p), 1024 threads = 16 waves.
// Phase 1: wave = channel c (wave-uniform); lane owns q-pair {2*lane, 2*lane+1}
//   packed in v2f. 7 packed VALU ops per k per thread (2 cells).
//   Weights + x_pp are wave-uniform -> scalar loads. x_qp / x_qq strided
//   (proven neutral vs transpose pre-pass in R3/R4).
// Diag: per-wave 64-lane shuffle reduce (mask q==p) -> s_diag.
// Phase 2: wave wv handles d = wv*8..wv*8+7 (wave-uniform -> scalar Wc/bc),
//   lane covers m-pair. ReLU + float2 streamed store.
// Grid 512 x 16 waves = 8192 waves = 100% machine wave capacity (2 blk/CU).
// ---------------------------------------------------------------------------
__global__ __launch_bounds__(1024, 8) void fused_rey(
    const float* __restrict__ x,
    const float* __restrict__ W1, const float* __restrict__ b1,
    const float* __restrict__ W2, const float* __restrict__ b2,
    const float* __restrict__ Wc, const float* __restrict__ bc,
    float* __restrict__ y)
{
    __shared__ float s_out[CCH][NN];   // 8 KB
    __shared__ float s_diag[CCH];

    const int t    = threadIdx.x;
    const int bid  = blockIdx.x;
    const int p    = bid & 127;
    const int b    = bid >> 7;
    const int c    = t >> 6;           // 0..15, wave-uniform
    const int lane = t & 63;
    const int q0   = lane * 2;         // q pair {q0, q0+1}

    const size_t mbase = (size_t)(b * CCH + c) << 14;
    const float* xm = x + mbase;

    // per-thread x loads
    const v2f xpq = *reinterpret_cast<const v2f*>(&xm[p * NN + q0]);   // coalesced
    const v2f xqp = { xm[q0 * NN + p], xm[(q0 + 1) * NN + p] };        // strided
    const v2f xqq = { xm[q0 * (NN + 1)], xm[(q0 + 1) * (NN + 1)] };    // strided
    const float xpp = xm[p * (NN + 1)];                                // wave-uniform
    const v2f xpp2 = { xpp, xpp };

    const float bb0 = b2[0], bb1 = b2[1];
    const v2f z2 = { 0.f, 0.f };
    v2f h0 = z2, h1 = z2;

    // ---- phase 1: hidden loop ----
    #pragma unroll 4
    for (int k = 0; k < HID; ++k) {
        const float4 w  = reinterpret_cast<const float4*>(W1)[k];  // uniform -> s_load
        const float b1k = b1[k];
        const float w20 = W2[k];
        const float w21 = W2[HID + k];
        v2f hd = __builtin_elementwise_fma((v2f){ w.x, w.x }, xpp2, (v2f){ b1k, b1k });
        hd = __builtin_elementwise_fma((v2f){ w.y, w.y }, xpq, hd);
        hd = __builtin_elementwise_fma((v2f){ w.z, w.z }, xqp, hd);
        hd = __builtin_elementwise_fma((v2f){ w.w, w.w }, xqq, hd);
        hd = __builtin_elementwise_max(hd, z2);
        h0 = __builtin_elementwise_fma((v2f){ w20, w20 }, hd, h0);
        h1 = __builtin_elementwise_fma((v2f){ w21, w21 }, hd, h1);
    }

    // off-diagonal h1 (+b2[1]) -> LDS row c; (c, p) slot fixed after barrier
    const v2f o = h1 + (v2f){ bb1, bb1 };
    *reinterpret_cast<v2f*>(&s_out[c][q0]) = o;

    // diag partial: mask q==p, 64-lane wave reduce
    float s = ((q0 == p) ? 0.f : h0[0]) + ((q0 + 1 == p) ? 0.f : h0[1]);
    #pragma unroll
    for (int off = 32; off > 0; off >>= 1)
        s += __shfl_down(s, off, 64);
    if (lane == 0) s_diag[c] = s * (1.0f / (NN - 1)) + bb0;

    __syncthreads();
    if (t < CCH) s_out[t][p] = s_diag[t];
    __syncthreads();

    // ---- phase 2: y[b,d,p,:] = relu(sum_c s_out[c]*Wc[d][c] + bc[d]) ----
    const int wv = t >> 6;             // 0..15 -> 8 d's each
    const int m0 = lane * 2;
    v2f r[CCH];
    #pragma unroll
    for (int cc = 0; cc < CCH; ++cc)
        r[cc] = *reinterpret_cast<const v2f*>(&s_out[cc][m0]);

    #pragma unroll 2
    for (int dd = 0; dd < 8; ++dd) {
        const int d = wv * 8 + dd;         // wave-uniform
        const float bcv = bc[d];           // scalar load
        v2f acc = { bcv, bcv };
        #pragma unroll
        for (int cc = 0; cc < CCH; ++cc) {
            const float wcf = Wc[d * CCH + cc];   // scalar load
            acc = __builtin_elementwise_fma((v2f){ wcf, wcf }, r[cc], acc);
        }
        acc = __builtin_elementwise_max(acc, z2);
        *reinterpret_cast<v2f*>(
            &y[(((size_t)(b * DOUT + d)) * NN + p) * NN + m0]) = acc;
    }
}

extern "C" void kernel_launch(void* const* d_in, const int* in_sizes, int n_in,
                              void* d_out, int out_size, void* d_ws, size_t ws_size,
                              hipStream_t stream) {
    const float* x  = (const float*)d_in[0];
    const float* W1 = (const float*)d_in[1];
    const float* b1 = (const float*)d_in[2];
    const float* W2 = (const float*)d_in[3];
    const float* b2 = (const float*)d_in[4];
    const float* Wc = (const float*)d_in[5];
    const float* bc = (const float*)d_in[6];
    float* y = (float*)d_out;

    fused_rey<<<dim3(BB * NN), 1024, 0, stream>>>(x, W1, b1, W2, b2, Wc, bc, y);
}